// Round 6
// baseline (550.141 us; speedup 1.0000x reference)
//
#include <hip/hip_runtime.h>
#include <math.h>

#pragma clang fp contract(off)

#define NBINS 36
#define PS 32

// Slim branchless f64 atan2, rounded to f32 (absmax 0.0 in R5 with the 3-way
// version; this is the 2-way variant). Reduction choice is computed in f32 —
// safe: near the threshold EITHER branch yields |xq| within the poly's
// accurate range (<=0.4375), so compare precision cannot change the rounded
// result. Total f64 relative error ~2^-50 -> round-to-f32 matches CR atan2
// except ~1 pixel in 64M -> argmax unaffected.
__device__ __forceinline__ float atan2_np(float fy, float fx)
{
    const double aT0  =  3.33333333333329318027e-01;
    const double aT1  = -1.99999999998764832476e-01;
    const double aT2  =  1.42857142725034663711e-01;
    const double aT3  = -1.11111104054623557880e-01;
    const double aT4  =  9.09088713343650656196e-02;
    const double aT5  = -7.69187620504482999495e-02;
    const double aT6  =  6.66107313738753120669e-02;
    const double aT7  = -5.83357013379057348645e-02;
    const double aT8  =  4.97687799461593236017e-02;
    const double aT9  = -3.65315727442169155270e-02;
    const double aT10 =  1.62858201153657823623e-02;

    float axf = fabsf(fx), ayf = fabsf(fy);
    float uf = fmaxf(axf, ayf), vf = fminf(axf, ayf);
    bool g1 = vf >= 0.41421356f * uf;          // ~tan(pi/8); slop harmless

    double u = (double)uf, v = (double)vf;
    double c      = g1 ? 1.0 : 0.0;
    double atc_hi = g1 ? 7.85398163397448278999e-01 : 0.0;
    double atc_lo = g1 ? 3.06161699786838301793e-17 : 0.0;

    double num = fma(-c, u, v);                // c=0: exactly v
    double den = fma(c, v, u);                 // c=0: exactly u

    double r0 = __builtin_amdgcn_rcp(den);
    r0 = fma(fma(-den, r0, 1.0), r0, r0);
    r0 = fma(fma(-den, r0, 1.0), r0, r0);
    double q0 = num * r0;
    double xq = fma(fma(-den, q0, num), r0, q0);   // ~0.5 ulp quotient
    // xq in [-0.1716, 0.4143] — inside fdlibm poly range [0, 0.4375]

    double z = xq * xq;
    double w = z * z;
    double s1_ = z * fma(w, fma(w, fma(w, fma(w, fma(w, aT10, aT8), aT6), aT4), aT2), aT0);
    double s2_ = w * fma(w, fma(w, fma(w, fma(w, aT9, aT7), aT5), aT3), aT1);
    double p   = xq * (s1_ + s2_);
    double res = atc_hi - ((p - atc_lo) - xq);     // angle of (u,v)

    double res2 = (1.57079632679489655800e+00 - res) + 6.12323399573676603587e-17;
    res = (ayf > axf) ? res2 : res;                // angle of (|x|,|y|)
    double res3 = (3.14159265358979311600e+00 - res) + 1.22464679914735317723e-16;
    res = (fx < 0.0f) ? res3 : res;                // x<0 half-plane
    res = copysign(res, (double)fy);
    return (float)res;
}

// One block = one patch. Bit-exact replication of the numpy reference:
//  - conv taps pre-scaled (exact pow2 products), summed ascending (kh,kw)
//  - mag = sqrt((gx*gx + gy*gy) + eps), contraction off
//  - atan2: slim f64 (above), rounded to f32
//  - histogram: per-bin sequential add chain in pixel order, w0 pass then
//    w1 pass (np.add.at semantics), via order-preserving counting sort.
// R6: transposed bitmap (b128 scan), packed u16 prefix table, float4 chain
// reads, parallel 36-lane epilogue + butterfly argmax (min-index ties ==
// np.argmax first-occurrence).
__global__ __launch_bounds__(256)
void patch_orient_kernel(const float* __restrict__ patches, float* __restrict__ out)
{
    __shared__ __align__(16) float tile[PS][PS];        // 4096 B
    __shared__ __align__(16) unsigned bm[NBINS][36];    // 5184 B  bm[bin][row], rows 0..31 used
    __shared__ __align__(16) unsigned pref32[NBINS][16];// 2304 B  u16 pair-packed prefix
    __shared__ unsigned short cnt[NBINS];               // 72 B
    __shared__ unsigned short start[NBINS];             // 72 B
    __shared__ __align__(16) float s0[1024];            // 4096 B  w0 sorted by (bin, pixel)
    __shared__ __align__(16) float s1[1024];            // 4096 B  w1, same permutation
    __shared__ float hsm[NBINS];                        // 144 B   -> total ~20.1 KB, 8 blk/CU

    const int t = threadIdx.x;
    const int b = blockIdx.x;
    const float* p = patches + (size_t)b * (PS * PS);

    // zero bitmap rows 0..31 of each bin (rows 32..35 never read/written)
    #pragma unroll
    for (int i = t; i < NBINS * 32; i += 256) bm[i >> 5][i & 31] = 0u;

    ((float4*)tile)[t] = ((const float4*)p)[t];         // coalesced 4 KiB load
    __syncthreads();

    // thread t owns pixels 4t..4t+3: row = t>>3, cols cb..cb+3
    const int row = t >> 3;
    const int cb  = (t & 7) << 2;
    const int rm  = (row == 0)  ? 0  : row - 1;
    const int rp  = (row == 31) ? 31 : row + 1;

    // 3 rows x 6 cols register window: b128 + 2 edge scalars per row
    float win[3][6];
    {
        const int cl = (cb == 0)  ? 0  : cb - 1;
        const int cr = (cb == 28) ? 31 : cb + 4;
        const int rows[3] = {rm, row, rp};
        #pragma unroll
        for (int r = 0; r < 3; ++r) {
            float4 v = *((const float4*)&tile[rows[r]][cb]);
            win[r][0] = tile[rows[r]][cl];
            win[r][1] = v.x; win[r][2] = v.y; win[r][3] = v.z; win[r][4] = v.w;
            win[r][5] = tile[rows[r]][cr];
        }
    }

    const float TWO_PI = 6.2831853071795864769f;   // f32(2*pi) == 2*f32(pi)
    const float PI_F   = 3.14159265358979323846f;

    float w0r[4], w1r[4];
    int   binr[4];

    #pragma unroll
    for (int i = 0; i < 4; ++i) {
        float A = win[0][i], B = win[0][i + 1], C = win[0][i + 2];
        float D = win[1][i],                    F = win[1][i + 2];
        float G = win[2][i], H = win[2][i + 1], I = win[2][i + 2];

        // pre-scaled taps (exact pow2 products), ascending (kh,kw) order
        float gx = -0.125f * A;
        gx += 0.125f  * C;
        gx += -0.25f  * D;
        gx += 0.25f   * F;
        gx += -0.125f * G;
        gx += 0.125f  * I;

        float gy = -0.125f * A;
        gy += -0.25f  * B;
        gy += -0.125f * C;
        gy += 0.125f  * G;
        gy += 0.25f   * H;
        gy += 0.125f  * I;

        float m1 = gx * gx;
        float m2 = gy * gy;
        float s  = m1 + m2;
        s = s + 1e-8f;
        float mag = sqrtf(s);                      // IEEE sqrt

        float gxe = gx + 1e-8f;
        float at  = atan2_np(gy, gxe);
        float ori = at + TWO_PI;
        float obig = (36.0f * (ori + PI_F)) / TWO_PI;
        float bo0  = floorf(obig);
        float wo1  = obig - bo0;                   // exact (Sterbenz)

        // bo0 provably in [35, 72]; fold to [0,36)
        int bi0 = (int)bo0 - 36;
        if (bi0 < 0)   bi0 += 36;                  // 35 -> 35
        if (bi0 >= 36) bi0 -= 36;                  // 72 -> 0

        w0r[i]  = (1.0f - wo1) * mag;
        w1r[i]  = wo1 * mag;
        binr[i] = bi0;
        atomicOr(&bm[bi0][row], 1u << (cb + i));
    }
    __syncthreads();

    // wave 0: per-bin prefix popcounts (b128 reads, packed u16-pair stores)
    if (t < 64) {
        unsigned run = 0;
        if (t < NBINS) {
            const uint4* bw = (const uint4*)&bm[t][0];
            uint4* pw = (uint4*)&pref32[t][0];
            #pragma unroll
            for (int k = 0; k < 4; ++k) {          // 8 rows per k
                uint4 wa = bw[2 * k], wb = bw[2 * k + 1];
                unsigned p0 = run;
                unsigned p1 = p0 + __popc(wa.x);
                unsigned p2 = p1 + __popc(wa.y);
                unsigned p3 = p2 + __popc(wa.z);
                unsigned p4 = p3 + __popc(wa.w);
                unsigned p5 = p4 + __popc(wb.x);
                unsigned p6 = p5 + __popc(wb.y);
                unsigned p7 = p6 + __popc(wb.z);
                run = p7 + __popc(wb.w);
                uint4 pk;
                pk.x = p0 | (p1 << 16);
                pk.y = p2 | (p3 << 16);
                pk.z = p4 | (p5 << 16);
                pk.w = p6 | (p7 << 16);
                pw[k] = pk;
            }
            cnt[t] = (unsigned short)run;
        }
        // exclusive prefix over bins (wave-wide shfl scan; lanes >=36 hold 0)
        unsigned v = run;
        #pragma unroll
        for (int d = 1; d < 64; d <<= 1) {
            unsigned o = (unsigned)__shfl_up((int)v, d);
            if (t >= d) v += o;
        }
        if (t < NBINS) start[t] = (unsigned short)(v - run);
    }
    __syncthreads();

    // scatter weights from registers into bin-sorted order (stable by pixel)
    #pragma unroll
    for (int i = 0; i < 4; ++i) {
        const int bi = binr[i];
        unsigned pv = pref32[bi][row >> 1];
        pv = (row & 1) ? (pv >> 16) : (pv & 0xffffu);
        const unsigned lowmask = (1u << (cb + i)) - 1u;
        const int pos = (int)start[bi] + (int)pv
                      + __popc(bm[bi][row] & lowmask);
        s0[pos] = w0r[i];
        s1[pos] = w1r[i];
    }
    __syncthreads();

    // exact np.add.at chains: bin t = (w0 run of bin t) then (w1 run of bin t-1)
    if (t < NBINS) {
        float acc = 0.0f;
        {
            int i = start[t], en = i + cnt[t];
            int lim = (i + 3) & ~3; if (lim > en) lim = en;
            for (; i < lim; ++i) acc += s0[i];                    // head <=3
            for (; i + 4 <= en; i += 4) {
                float4 v4 = *((const float4*)&s0[i]);
                acc += v4.x; acc += v4.y; acc += v4.z; acc += v4.w;
            }
            for (; i < en; ++i) acc += s0[i];                     // tail <=3
        }
        {
            int t2 = (t == 0) ? NBINS - 1 : t - 1;
            int i = start[t2], en = i + cnt[t2];
            int lim = (i + 3) & ~3; if (lim > en) lim = en;
            for (; i < lim; ++i) acc += s1[i];
            for (; i + 4 <= en; i += 4) {
                float4 v4 = *((const float4*)&s1[i]);
                acc += v4.x; acc += v4.y; acc += v4.z; acc += v4.w;
            }
            for (; i < en; ++i) acc += s1[i];
        }
        hsm[t] = acc * (1.0f / 1024.0f);           // /npix, exact pow2
    }
    __syncthreads();

    // parallel smoothing + butterfly argmax (min index on ties == np.argmax)
    if (t < 64) {
        float val = -1.0f;                          // all sm >= 0
        int   idx = t;
        if (t < NBINS) {
            int im_ = (t == 0)         ? NBINS - 1 : t - 1;
            int ip_ = (t == NBINS - 1) ? 0         : t + 1;
            float q0 = 0.33f * hsm[im_];
            float q1 = 0.34f * hsm[t];
            float q2 = 0.33f * hsm[ip_];
            val = (q0 + q1) + q2;                   // left-to-right, no FMA
        }
        #pragma unroll
        for (int d = 1; d < 64; d <<= 1) {
            float ov = __shfl_xor(val, d);
            int   oi = __shfl_xor(idx, d);
            if (ov > val || (ov == val && oi < idx)) { val = ov; idx = oi; }
        }
        if (t == 0) {
            float t1 = TWO_PI * (float)idx;
            float t2 = t1 / 36.0f;
            float t3 = t2 - PI_F;
            out[b] = -t3;
        }
    }
}

extern "C" void kernel_launch(void* const* d_in, const int* in_sizes, int n_in,
                              void* d_out, int out_size, void* d_ws, size_t ws_size,
                              hipStream_t stream) {
    const float* patch = (const float*)d_in[0];
    float* out = (float*)d_out;
    const int B = in_sizes[0] / (PS * PS);   // 65536 patches
    patch_orient_kernel<<<B, 256, 0, stream>>>(patch, out);
}

// Round 7
// 522.821 us; speedup vs baseline: 1.0523x; 1.0523x over previous
//
#include <hip/hip_runtime.h>
#include <math.h>

#pragma clang fp contract(off)

#define NBINS 36
#define PS 32

// Slim branchless f64 atan2, rounded to f32 (absmax 0.0 R5/R6).
__device__ __forceinline__ float atan2_np(float fy, float fx)
{
    const double aT0  =  3.33333333333329318027e-01;
    const double aT1  = -1.99999999998764832476e-01;
    const double aT2  =  1.42857142725034663711e-01;
    const double aT3  = -1.11111104054623557880e-01;
    const double aT4  =  9.09088713343650656196e-02;
    const double aT5  = -7.69187620504482999495e-02;
    const double aT6  =  6.66107313738753120669e-02;
    const double aT7  = -5.83357013379057348645e-02;
    const double aT8  =  4.97687799461593236017e-02;
    const double aT9  = -3.65315727442169155270e-02;
    const double aT10 =  1.62858201153657823623e-02;

    float axf = fabsf(fx), ayf = fabsf(fy);
    float uf = fmaxf(axf, ayf), vf = fminf(axf, ayf);
    bool g1 = vf >= 0.41421356f * uf;          // ~tan(pi/8); either branch valid near cut

    double u = (double)uf, v = (double)vf;
    double c      = g1 ? 1.0 : 0.0;
    double atc_hi = g1 ? 7.85398163397448278999e-01 : 0.0;
    double atc_lo = g1 ? 3.06161699786838301793e-17 : 0.0;

    double num = fma(-c, u, v);                // c=0: exactly v
    double den = fma(c, v, u);                 // c=0: exactly u

    double r0 = __builtin_amdgcn_rcp(den);
    r0 = fma(fma(-den, r0, 1.0), r0, r0);
    r0 = fma(fma(-den, r0, 1.0), r0, r0);
    double q0 = num * r0;
    double xq = fma(fma(-den, q0, num), r0, q0);   // ~0.5 ulp quotient
    // xq in [-0.1716, 0.4143] — inside fdlibm poly range [0, 0.4375]

    double z = xq * xq;
    double w = z * z;
    double s1_ = z * fma(w, fma(w, fma(w, fma(w, fma(w, aT10, aT8), aT6), aT4), aT2), aT0);
    double s2_ = w * fma(w, fma(w, fma(w, fma(w, aT9, aT7), aT5), aT3), aT1);
    double p   = xq * (s1_ + s2_);
    double res = atc_hi - ((p - atc_lo) - xq);     // angle of (u,v)

    double res2 = (1.57079632679489655800e+00 - res) + 6.12323399573676603587e-17;
    res = (ayf > axf) ? res2 : res;                // angle of (|x|,|y|)
    double res3 = (3.14159265358979311600e+00 - res) + 1.22464679914735317723e-16;
    res = (fx < 0.0f) ? res3 : res;                // x<0 half-plane
    res = copysign(res, (double)fy);
    return (float)res;
}

// DPP lane-shift helpers (VALU, no LDS): value of lane-1 / lane+1 within
// 16-lane DPP rows. Lanes receiving cross-row garbage are exactly the
// edge-clamped ones (cb==0 / cb==28), overridden by the caller's select.
__device__ __forceinline__ float dpp_prev(float x) {
    int i = __builtin_bit_cast(int, x);
    int r = __builtin_amdgcn_update_dpp(i, i, 0x111, 0xf, 0xf, false); // row_shr:1
    return __builtin_bit_cast(float, r);
}
__device__ __forceinline__ float dpp_next(float x) {
    int i = __builtin_bit_cast(int, x);
    int r = __builtin_amdgcn_update_dpp(i, i, 0x101, 0xf, 0xf, false); // row_shl:1
    return __builtin_bit_cast(float, r);
}

// One block = one patch. Bit-exact replication of the numpy reference:
//  - conv taps pre-scaled (exact pow2 products), summed ascending (kh,kw)
//  - mag = sqrt((gx*gx + gy*gy) + eps), contraction off
//  - atan2: slim f64 (above), rounded to f32
//  - /2pi division: Markstein (rcp + fma correction) — 1-ulp-rare class
//  - histogram: per-bin sequential add chain in pixel order, w0 pass then
//    w1 pass (np.add.at semantics), via order-preserving counting sort.
// R7: R5's LDS layouts (row-major bitmap, u16 prefix, scalar chain — known
// 4.3e7 conflict profile) + R6's parallel epilogue + DPP window edges.
__global__ __launch_bounds__(256)
void patch_orient_kernel(const float* __restrict__ patches, float* __restrict__ out)
{
    __shared__ __align__(16) float tile[PS][PS];       // 4 KiB
    __shared__ unsigned bm[PS][NBINS];                 // 4.5 KiB  bm[row][bin]
    __shared__ unsigned short pref[PS][NBINS];         // 2.25 KiB word-prefix popcounts
    __shared__ unsigned short cnt[NBINS];
    __shared__ unsigned short start[NBINS];
    __shared__ __align__(16) float s0[1024];           // w0 sorted by (bin, pixel)
    __shared__ __align__(16) float s1[1024];           // w1, same permutation
    __shared__ float hsm[NBINS];

    const int t = threadIdx.x;
    const int b = blockIdx.x;
    const float* p = patches + (size_t)b * (PS * PS);

    #pragma unroll
    for (int i = t; i < PS * NBINS; i += 256) ((unsigned*)bm)[i] = 0u;

    ((float4*)tile)[t] = ((const float4*)p)[t];        // coalesced 4 KiB load
    __syncthreads();

    // thread t owns pixels 4t..4t+3: row = t>>3, cols cb..cb+3
    const int row = t >> 3;
    const int cb  = (t & 7) << 2;
    const int rm  = (row == 0)  ? 0  : row - 1;
    const int rp  = (row == 31) ? 31 : row + 1;

    // 3 rows x 6 cols window: one b128 per row + DPP for the two edge cols
    float win[3][6];
    {
        const int rows[3] = {rm, row, rp};
        #pragma unroll
        for (int r = 0; r < 3; ++r) {
            float4 v = *((const float4*)&tile[rows[r]][cb]);
            float lf = dpp_prev(v.w);              // lane-1's col cb-1
            float rt = dpp_next(v.x);              // lane+1's col cb+4
            win[r][0] = (cb == 0)  ? v.x : lf;     // edge clamp col 0
            win[r][1] = v.x; win[r][2] = v.y; win[r][3] = v.z; win[r][4] = v.w;
            win[r][5] = (cb == 28) ? v.w : rt;     // edge clamp col 31
        }
    }

    const float TWO_PI = 6.2831853071795864769f;   // f32(2*pi) == 2*f32(pi)
    const float PI_F   = 3.14159265358979323846f;
    const float INV2PI = 0.15915493667125701904f;  // RN_f32(1 / f32(2*pi))

    float w0r[4], w1r[4];
    int   binr[4];

    #pragma unroll
    for (int i = 0; i < 4; ++i) {
        float A = win[0][i], B = win[0][i + 1], C = win[0][i + 2];
        float D = win[1][i],                    F = win[1][i + 2];
        float G = win[2][i], H = win[2][i + 1], I = win[2][i + 2];

        // pre-scaled taps (exact pow2 products), ascending (kh,kw) order
        float gx = -0.125f * A;
        gx += 0.125f  * C;
        gx += -0.25f  * D;
        gx += 0.25f   * F;
        gx += -0.125f * G;
        gx += 0.125f  * I;

        float gy = -0.125f * A;
        gy += -0.25f  * B;
        gy += -0.125f * C;
        gy += 0.125f  * G;
        gy += 0.25f   * H;
        gy += 0.125f  * I;

        float m1 = gx * gx;
        float m2 = gy * gy;
        float s  = m1 + m2;
        s = s + 1e-8f;
        float mag = sqrtf(s);                      // IEEE sqrt

        float gxe = gx + 1e-8f;
        float at  = atan2_np(gy, gxe);
        float ori = at + TWO_PI;
        float xn  = 36.0f * (ori + PI_F);
        // Markstein correctly-rounded-division surrogate for xn / TWO_PI
        float q1m = xn * INV2PI;
        float obig = fmaf(fmaf(-TWO_PI, q1m, xn), INV2PI, q1m);
        float bo0  = floorf(obig);
        float wo1  = obig - bo0;                   // exact (Sterbenz)

        // bo0 provably in [35, 72]; fold to [0,36)
        int bi0 = (int)bo0 - 36;
        if (bi0 < 0)   bi0 += 36;                  // 35 -> 35
        if (bi0 >= 36) bi0 -= 36;                  // 72 -> 0

        w0r[i]  = (1.0f - wo1) * mag;
        w1r[i]  = wo1 * mag;
        binr[i] = bi0;
        atomicOr(&bm[row][bi0], 1u << (cb + i));
    }
    __syncthreads();

    // wave 0: per-bin word-prefix popcounts + counts + bin-start prefix
    if (t < 64) {
        unsigned run = 0;
        if (t < NBINS) {
            #pragma unroll 1
            for (int w = 0; w < PS; ++w) {
                pref[w][t] = (unsigned short)run;
                run += __popc(bm[w][t]);
            }
            cnt[t] = (unsigned short)run;
        }
        // exclusive prefix over bins (wave-wide shfl scan; lanes >=36 hold 0)
        unsigned v = run;
        #pragma unroll
        for (int d = 1; d < 64; d <<= 1) {
            unsigned o = (unsigned)__shfl_up((int)v, d);
            if (t >= d) v += o;
        }
        if (t < NBINS) start[t] = (unsigned short)(v - run);
    }
    __syncthreads();

    // scatter weights from registers into bin-sorted order (stable by pixel)
    #pragma unroll
    for (int i = 0; i < 4; ++i) {
        const int bi = binr[i];
        const unsigned lowmask = (1u << (cb + i)) - 1u;
        const int pos = (int)start[bi] + (int)pref[row][bi]
                      + __popc(bm[row][bi] & lowmask);
        s0[pos] = w0r[i];
        s1[pos] = w1r[i];
    }
    __syncthreads();

    // exact np.add.at chains: bin t = (w0 run of bin t) then (w1 run of bin t-1)
    if (t < NBINS) {
        float acc = 0.0f;
        {
            int i = start[t], en = i + cnt[t];
            for (; i + 1 < en; i += 2) { acc += s0[i]; acc += s0[i + 1]; }
            if (i < en) acc += s0[i];
        }
        {
            int t2 = (t == 0) ? NBINS - 1 : t - 1;
            int i = start[t2], en = i + cnt[t2];
            for (; i + 1 < en; i += 2) { acc += s1[i]; acc += s1[i + 1]; }
            if (i < en) acc += s1[i];
        }
        hsm[t] = acc * (1.0f / 1024.0f);           // /npix, exact pow2
    }
    __syncthreads();

    // parallel smoothing + butterfly argmax (min index on ties == np.argmax)
    if (t < 64) {
        float val = -1.0f;                          // all sm >= 0
        int   idx = t;
        if (t < NBINS) {
            int im_ = (t == 0)         ? NBINS - 1 : t - 1;
            int ip_ = (t == NBINS - 1) ? 0         : t + 1;
            float q0 = 0.33f * hsm[im_];
            float q1 = 0.34f * hsm[t];
            float q2 = 0.33f * hsm[t == NBINS - 1 ? 0 : t + 1] * 0.0f + 0.33f * hsm[ip_];
            val = (q0 + q1) + q2;                   // left-to-right, no FMA
        }
        #pragma unroll
        for (int d = 1; d < 64; d <<= 1) {
            float ov = __shfl_xor(val, d);
            int   oi = __shfl_xor(idx, d);
            if (ov > val || (ov == val && oi < idx)) { val = ov; idx = oi; }
        }
        if (t == 0) {
            float t1 = TWO_PI * (float)idx;
            float t2 = t1 / 36.0f;
            float t3 = t2 - PI_F;
            out[b] = -t3;
        }
    }
}

extern "C" void kernel_launch(void* const* d_in, const int* in_sizes, int n_in,
                              void* d_out, int out_size, void* d_ws, size_t ws_size,
                              hipStream_t stream) {
    const float* patch = (const float*)d_in[0];
    float* out = (float*)d_out;
    const int B = in_sizes[0] / (PS * PS);   // 65536 patches
    patch_orient_kernel<<<B, 256, 0, stream>>>(patch, out);
}